// Round 1
// baseline (224.114 us; speedup 1.0000x reference)
//
#include <hip/hip_runtime.h>

// Gray-Scott PDE residual:
//   u = in[:, :, 1], v = in[:, :, 2]           (T=20, B=8, C=3, H=256, W=256) fp32
//   lap  = 4th-order 5-pt-per-axis Laplacian / DX^2 on the HxW plane (VALID -> 252x252)
//   u_t  = central diff over T (2nd-order one-sided at t=0, t=19), / DT
//   f_u  = Du*lap_u - u*v^2 + f*(1-u) - u_t
//   f_v  = Dv*lap_v + u*v^2 - (f+k)*v - v_t
// Output: [f_u flat | f_v flat], each (20,8,1,252,252) fp32.

#define IN_W   256
#define IN_H   256
#define OUT_W  252
#define OUT_H  252
#define T_DIM  20
#define B_DIM  8

__global__ __launch_bounds__(256) void gs_loss_kernel(
    const float* __restrict__ in, float* __restrict__ out, int total)
{
    int idx = blockIdx.x * blockDim.x + threadIdx.x;
    if (idx >= total) return;

    int x    = idx % OUT_W;
    int rest = idx / OUT_W;
    int y    = rest % OUT_H;
    int tb   = rest / OUT_H;
    int b    = tb & 7;         // B_DIM = 8
    int t    = tb >> 3;

    const int planeStride = IN_H * IN_W;        // 65536
    const int bStride     = 3 * planeStride;    // 196608
    const int tStride     = B_DIM * bStride;    // 1572864

    const float* __restrict__ up = in + (long)t * tStride + (long)b * bStride + planeStride;      // channel 1
    const float* __restrict__ vp = up + planeStride;                                              // channel 2

    int off = (y + 2) * IN_W + (x + 2);   // stencil center in the 256x256 plane

    // ---- 5-point-per-axis Laplacian (cross stencil) ----
    float uc = up[off];
    float vc = vp[off];

    const float c1 = 4.0f / 3.0f;
    const float c2 = 1.0f / 12.0f;

    float lap_u = c1 * (up[off - 1] + up[off + 1] + up[off - IN_W] + up[off + IN_W])
                - c2 * (up[off - 2] + up[off + 2] + up[off - 2 * IN_W] + up[off + 2 * IN_W])
                - 5.0f * uc;
    float lap_v = c1 * (vp[off - 1] + vp[off + 1] + vp[off - IN_W] + vp[off + IN_W])
                - c2 * (vp[off - 2] + vp[off + 2] + vp[off - 2 * IN_W] + vp[off + 2 * IN_W])
                - 5.0f * vc;

    const float inv_dx2 = 1.0f / (0.15625f * 0.15625f);   // DX = 20/128 exactly
    lap_u *= inv_dx2;
    lap_v *= inv_dx2;

    // ---- time derivative across T ----
    const float inv_dt = 20.0f;   // 1/DT, DT = 0.05 exactly
    float u_t, v_t;
    if (t == 0) {
        float u1 = up[off + tStride], u2 = up[off + 2 * tStride];
        float v1 = vp[off + tStride], v2 = vp[off + 2 * tStride];
        u_t = (-1.5f * uc + 2.0f * u1 - 0.5f * u2) * inv_dt;
        v_t = (-1.5f * vc + 2.0f * v1 - 0.5f * v2) * inv_dt;
    } else if (t == T_DIM - 1) {
        float um1 = up[off - tStride], um2 = up[off - 2 * tStride];
        float vm1 = vp[off - tStride], vm2 = vp[off - 2 * tStride];
        u_t = (0.5f * um2 - 2.0f * um1 + 1.5f * uc) * inv_dt;
        v_t = (0.5f * vm2 - 2.0f * vm1 + 1.5f * vc) * inv_dt;
    } else {
        u_t = (up[off + tStride] - up[off - tStride]) * (0.5f * inv_dt);
        v_t = (vp[off + tStride] - vp[off - tStride]) * (0.5f * inv_dt);
    }

    // ---- reaction terms ----
    const float Du = 0.16f, Dv = 0.08f, fRate = 0.06f, kRate = 0.062f;
    float uvv = uc * vc * vc;
    float f_u = Du * lap_u - uvv + fRate * (1.0f - uc) - u_t;
    float f_v = Dv * lap_v + uvv - (fRate + kRate) * vc - v_t;

    out[idx]         = f_u;
    out[idx + total] = f_v;
}

extern "C" void kernel_launch(void* const* d_in, const int* in_sizes, int n_in,
                              void* d_out, int out_size, void* d_ws, size_t ws_size,
                              hipStream_t stream) {
    const float* in = (const float*)d_in[0];
    float* out = (float*)d_out;

    const int total = T_DIM * B_DIM * OUT_H * OUT_W;   // 10,160,640 per output tensor
    const int threads = 256;
    const int blocks = (total + threads - 1) / threads;
    gs_loss_kernel<<<blocks, threads, 0, stream>>>(in, out, total);
}